// Round 1
// 1810.257 us; speedup vs baseline: 1.1078x; 1.1078x over previous
//
#include <hip/hip_runtime.h>
#include <cstdint>
#include <cstddef>

#define T_LEN   4096
#define B_SZ    32
#define H_DIM   128
#define DX      128
#define K_CLS   10
#define CHUNK   32
#define NCHUNKS (T_LEN / CHUNK)
#define XA_LD   136   // f16 per xA row (pad: 272B stride -> 2-way max on b128 reads)
#define XP_LD   408   // f16 per xp row (pad: 816B stride -> 2-way max on epilogue writes)
#define HI_LD   136

typedef _Float16 half8   __attribute__((ext_vector_type(8)));
typedef float    floatx4 __attribute__((ext_vector_type(4)));

__device__ __forceinline__ float sigm(float x) {
  x = fminf(fmaxf(x, -30.f), 30.f);
  return __builtin_amdgcn_rcpf(1.f + __expf(-x));
}

__device__ __forceinline__ float tanhfast(float x) {
  x = fminf(fmaxf(x, -15.f), 15.f);
  float t = __expf(-2.f * x);
  return (1.f - t) * __builtin_amdgcn_rcpf(1.f + t);
}

__global__ void __launch_bounds__(256) init_out_kernel(float* __restrict__ out,
                                                       const float* __restrict__ bfc) {
  int i = blockIdx.x * 256 + threadIdx.x;
  if (i < B_SZ * T_LEN * K_CLS) out[i] = bfc[i % K_CLS];
}

// One block per (batch, direction) scan. 8 waves (512 threads):
//  - recurrent matvec hp = Whh @ h via MFMA, Whh stationary in VGPRs
//    (wave w owns hidden slice j in [16w, 16w+16) for all 3 gates)
//  - h lives in LDS row hist[s][*] (f16), read as MFMA A-operand by 4 lanes/wave
//  - x-projection (x @ Wih^T + biases) per 32-step chunk via MFMA, Wih stationary
//  - fused FC on hist + atomicAdd into pre-biased out
__global__ void __launch_bounds__(512, 2)
gru_bidir_kernel(const float* __restrict__ x,
                 const float* __restrict__ Wih_f, const float* __restrict__ Whh_f,
                 const float* __restrict__ bih_f, const float* __restrict__ bhh_f,
                 const float* __restrict__ Wih_b, const float* __restrict__ Whh_b,
                 const float* __restrict__ bih_b, const float* __restrict__ bhh_b,
                 const float* __restrict__ Wfc, float* __restrict__ out) {
  const int tid = threadIdx.x;
  const int bid = blockIdx.x;
  const int b   = bid & (B_SZ - 1);
  const int dir = bid >> 5;

  const float* Wih = dir ? Wih_b : Wih_f;
  const float* Whh = dir ? Whh_b : Whh_f;
  const float* bih = dir ? bih_b : bih_f;
  const float* bhh = dir ? bhh_b : bhh_f;

  const int lane = tid & 63;
  const int wv   = tid >> 6;      // 0..7
  const int col  = lane & 15;     // MFMA n / m index
  const int quad = lane >> 4;     // MFMA k-group / row-group
  const int jloc = wv * 16 + col; // this lane's hidden unit (column) for its wave's slice

  __shared__ __align__(16) _Float16 xA[CHUNK][XA_LD];        // staged x chunk (f16)
  __shared__ __align__(16) _Float16 xPL[CHUNK][XP_LD];       // x @ Wih^T + bias, [s][3*128]
  __shared__ __align__(16) _Float16 hist[CHUNK + 1][HI_LD];  // h per step; row 0 = carry-in

  // ---- stationary weight fragments: B-operand layout (n=col, k=kt*32+quad*8+e) ----
  half8 whf[3][4];   // Whh^T fragments: 48 VGPR
  half8 wif[3][4];   // Wih^T fragments: 48 VGPR
#pragma unroll
  for (int g = 0; g < 3; ++g) {
#pragma unroll
    for (int kt = 0; kt < 4; ++kt) {
      const float* sh = Whh + (size_t)(g * H_DIM + jloc) * H_DIM + kt * 32 + quad * 8;
      const float* si = Wih + (size_t)(g * H_DIM + jloc) * DX + kt * 32 + quad * 8;
      half8 vh, vi;
#pragma unroll
      for (int e = 0; e < 8; ++e) {
        vh[e] = (_Float16)sh[e];
        vi[e] = (_Float16)si[e];
      }
      whf[g][kt] = vh;
      wif[g][kt] = vi;
    }
  }
  const float bias_r = bih[jloc] + bhh[jloc];
  const float bias_z = bih[H_DIM + jloc] + bhh[H_DIM + jloc];
  const float bias_n = bih[2 * H_DIM + jloc];
  const float bhn    = bhh[2 * H_DIM + jloc];

  // ---- Wfc fragments for fused FC (waves 0..1 only) ----
  half8 fcf[4];
  if (wv < 2) {
#pragma unroll
    for (int kt = 0; kt < 4; ++kt) {
      half8 v;
#pragma unroll
      for (int e = 0; e < 8; ++e) {
        int k = kt * 32 + quad * 8 + e;
        v[e] = (col < K_CLS) ? (_Float16)Wfc[(size_t)col * (2 * H_DIM) + dir * H_DIM + k]
                             : (_Float16)0.f;
      }
      fcf[kt] = v;
    }
  }

  // A-operand fragments for the recurrent matvec; only lanes with col==0 ever load
  // them (row 0 of the 16-row A tile); all other lanes stay zero.
  half8 hz;
#pragma unroll
  for (int e = 0; e < 8; ++e) hz[e] = (_Float16)0.f;
  half8 haf0 = hz, haf1 = hz, haf2 = hz, haf3 = hz;

  if (tid < H_DIM) hist[0][tid] = (_Float16)0.f;

  // ---- x prefetch: thread covers row s_row, 8 consecutive floats ----
  const int s_row = tid >> 4;        // 0..31
  const int cb    = (tid & 15) * 8;  // 0..120
  float4 px0, px1;
  {
    int t0 = dir ? (T_LEN - 1 - s_row) : s_row;
    const float* xr = x + ((size_t)b * T_LEN + t0) * DX + cb;
    px0 = *(const float4*)xr;
    px1 = *(const float4*)(xr + 4);
  }

  float hold = 0.f;  // carried h for unit jloc (valid in quad==0 lanes)
  const floatx4 z4 = {0.f, 0.f, 0.f, 0.f};
  __syncthreads();

  for (int c = 0; c < NCHUNKS; ++c) {
    // ---- stage x chunk into LDS (f16) ----
    {
      half8 v;
      v[0] = (_Float16)px0.x; v[1] = (_Float16)px0.y; v[2] = (_Float16)px0.z; v[3] = (_Float16)px0.w;
      v[4] = (_Float16)px1.x; v[5] = (_Float16)px1.y; v[6] = (_Float16)px1.z; v[7] = (_Float16)px1.w;
      *(half8*)&xA[s_row][cb] = v;
    }
    __syncthreads();

    // ---- xp = x @ Wih^T + bias for this chunk (MFMA) ----
#pragma unroll
    for (int mt = 0; mt < 2; ++mt) {
      half8 af[4];
#pragma unroll
      for (int kt = 0; kt < 4; ++kt)
        af[kt] = *(const half8*)&xA[mt * 16 + col][kt * 32 + quad * 8];
#pragma unroll
      for (int g = 0; g < 3; ++g) {
        floatx4 a = z4;
#pragma unroll
        for (int kt = 0; kt < 4; ++kt)
          a = __builtin_amdgcn_mfma_f32_16x16x32_f16(af[kt], wif[g][kt], a, 0, 0, 0);
        float bb = (g == 0) ? bias_r : (g == 1) ? bias_z : bias_n;
#pragma unroll
        for (int i = 0; i < 4; ++i)
          xPL[mt * 16 + quad * 4 + i][g * H_DIM + jloc] = (_Float16)(a[i] + bb);
      }
    }

    // prefetch next chunk's x (drains at the first scan barrier)
    if (c + 1 < NCHUNKS) {
      int s  = (c + 1) * CHUNK + s_row;
      int t0 = dir ? (T_LEN - 1 - s) : s;
      const float* xr = x + ((size_t)b * T_LEN + t0) * DX + cb;
      px0 = *(const float4*)xr;
      px1 = *(const float4*)(xr + 4);
    }
    __syncthreads();

    // ---- sequential scan: hp = Whh @ h via MFMA (row 0 of A is h) ----
#pragma unroll 2
    for (int s = 0; s < CHUNK; ++s) {
      if (col == 0) {
        haf0 = *(const half8*)&hist[s][quad * 8];
        haf1 = *(const half8*)&hist[s][32 + quad * 8];
        haf2 = *(const half8*)&hist[s][64 + quad * 8];
        haf3 = *(const half8*)&hist[s][96 + quad * 8];
      }
      // two 2-deep K-chains per gate to shorten the dependency chain
      floatx4 arA = __builtin_amdgcn_mfma_f32_16x16x32_f16(haf0, whf[0][0], z4, 0, 0, 0);
      arA = __builtin_amdgcn_mfma_f32_16x16x32_f16(haf1, whf[0][1], arA, 0, 0, 0);
      floatx4 arB = __builtin_amdgcn_mfma_f32_16x16x32_f16(haf2, whf[0][2], z4, 0, 0, 0);
      arB = __builtin_amdgcn_mfma_f32_16x16x32_f16(haf3, whf[0][3], arB, 0, 0, 0);

      floatx4 azA = __builtin_amdgcn_mfma_f32_16x16x32_f16(haf0, whf[1][0], z4, 0, 0, 0);
      azA = __builtin_amdgcn_mfma_f32_16x16x32_f16(haf1, whf[1][1], azA, 0, 0, 0);
      floatx4 azB = __builtin_amdgcn_mfma_f32_16x16x32_f16(haf2, whf[1][2], z4, 0, 0, 0);
      azB = __builtin_amdgcn_mfma_f32_16x16x32_f16(haf3, whf[1][3], azB, 0, 0, 0);

      floatx4 anA = __builtin_amdgcn_mfma_f32_16x16x32_f16(haf0, whf[2][0], z4, 0, 0, 0);
      anA = __builtin_amdgcn_mfma_f32_16x16x32_f16(haf1, whf[2][1], anA, 0, 0, 0);
      floatx4 anB = __builtin_amdgcn_mfma_f32_16x16x32_f16(haf2, whf[2][2], z4, 0, 0, 0);
      anB = __builtin_amdgcn_mfma_f32_16x16x32_f16(haf3, whf[2][3], anB, 0, 0, 0);

      float ar = arA[0] + arB[0];   // valid in quad==0 lanes (D row 0)
      float az = azA[0] + azB[0];
      float an = anA[0] + anB[0];

      float xr = (float)xPL[s][jloc];
      float xz = (float)xPL[s][H_DIM + jloc];
      float xn = (float)xPL[s][2 * H_DIM + jloc];

      float rr = sigm(xr + ar);
      float zz = sigm(xz + az);
      float nn = tanhfast(xn + rr * (an + bhn));
      hold = nn + zz * (hold - nn);

      if (quad == 0) hist[s + 1][jloc] = (_Float16)hold;
      __syncthreads();
    }

    // ---- fused FC for this chunk (waves 0..1) ----
    if (wv < 2) {
      floatx4 fa = z4;
#pragma unroll
      for (int kt = 0; kt < 4; ++kt) {
        half8 af = *(const half8*)&hist[1 + wv * 16 + col][kt * 32 + quad * 8];
        fa = __builtin_amdgcn_mfma_f32_16x16x32_f16(af, fcf[kt], fa, 0, 0, 0);
      }
      if (col < K_CLS) {
#pragma unroll
        for (int i = 0; i < 4; ++i) {
          int t  = c * CHUNK + wv * 16 + quad * 4 + i;
          int tt = dir ? (T_LEN - 1 - t) : t;
          atomicAdd(out + ((size_t)b * T_LEN + tt) * K_CLS + col, fa[i]);
        }
      }
    }
    // carry h into row 0 for the next chunk (ordered by next chunk's stage barrier)
    if (tid >= 256 && tid < 256 + H_DIM) hist[0][tid - 256] = hist[CHUNK][tid - 256];
  }
}

extern "C" void kernel_launch(void* const* d_in, const int* in_sizes, int n_in,
                              void* d_out, int out_size, void* d_ws, size_t ws_size,
                              hipStream_t stream) {
  (void)in_sizes; (void)n_in; (void)d_ws; (void)ws_size; (void)out_size;
  const float* x     = (const float*)d_in[0];
  const float* Wih_f = (const float*)d_in[1];
  const float* Whh_f = (const float*)d_in[2];
  const float* bih_f = (const float*)d_in[3];
  const float* bhh_f = (const float*)d_in[4];
  const float* Wih_b = (const float*)d_in[5];
  const float* Whh_b = (const float*)d_in[6];
  const float* bih_b = (const float*)d_in[7];
  const float* bhh_b = (const float*)d_in[8];
  const float* Wfc   = (const float*)d_in[9];
  const float* bfc   = (const float*)d_in[10];
  float* out = (float*)d_out;

  const int n_out = B_SZ * T_LEN * K_CLS;
  init_out_kernel<<<(n_out + 255) / 256, 256, 0, stream>>>(out, bfc);
  gru_bidir_kernel<<<B_SZ * 2, 512, 0, stream>>>(x, Wih_f, Whh_f, bih_f, bhh_f,
                                                 Wih_b, Whh_b, bih_b, bhh_b, Wfc, out);
}

// Round 2
// 1724.380 us; speedup vs baseline: 1.1630x; 1.0498x over previous
//
#include <hip/hip_runtime.h>
#include <cstdint>
#include <cstddef>

#define T_LEN   4096
#define B_SZ    32
#define H_DIM   128
#define DX      128
#define K_CLS   10
#define CHUNK   32
#define NCHUNKS (T_LEN / CHUNK)
#define XA_LD   136   // f16 per xA row
#define XP_LD   520   // f16 per xPL row: 128 units * 4 (r,z,n,pad) + 8 pad
#define HI_LD   136

typedef _Float16 half2v  __attribute__((ext_vector_type(2)));
typedef _Float16 half4   __attribute__((ext_vector_type(4)));
typedef _Float16 half8   __attribute__((ext_vector_type(8)));
typedef float    floatx4 __attribute__((ext_vector_type(4)));

// Raw barrier: orders LDS ops only (no vmcnt drain). Compiler fences on both
// sides keep ds ops from being moved across (m201-verified pattern).
#define LGKM_BARRIER() do {                                   \
    asm volatile("s_waitcnt lgkmcnt(0)" ::: "memory");        \
    __builtin_amdgcn_s_barrier();                             \
    asm volatile("" ::: "memory");                            \
  } while (0)

__global__ void __launch_bounds__(256) init_out_kernel(float* __restrict__ out,
                                                       const float* __restrict__ bfc) {
  int i = blockIdx.x * 256 + threadIdx.x;
  if (i < B_SZ * T_LEN * K_CLS) out[i] = bfc[i % K_CLS];
}

// One block per (batch, direction) scan. 8 waves (512 threads):
//  - recurrent matvec hp = Whh @ h via MFMA, Whh stationary in VGPRs
//    (wave w owns hidden slice j in [16w,16w+16) for all 3 gates)
//  - weights pre-scaled by log2e (r,z) / 2*log2e (n) so gates use raw v_exp
//  - h lives in LDS row hist[s][*] (f16), read as MFMA A-operand by 4 lanes/wave
//  - xp packed [s][j*4+g], one b64 read/step, prefetched one step ahead
//  - raw lgkm-only barriers in the scan (no vmcnt drains on the critical path)
__global__ void __launch_bounds__(512, 2)
gru_bidir_kernel(const float* __restrict__ x,
                 const float* __restrict__ Wih_f, const float* __restrict__ Whh_f,
                 const float* __restrict__ bih_f, const float* __restrict__ bhh_f,
                 const float* __restrict__ Wih_b, const float* __restrict__ Whh_b,
                 const float* __restrict__ bih_b, const float* __restrict__ bhh_b,
                 const float* __restrict__ Wfc, float* __restrict__ out) {
  const int tid = threadIdx.x;
  const int bid = blockIdx.x;
  const int b   = bid & (B_SZ - 1);
  const int dir = bid >> 5;

  const float* Wih = dir ? Wih_b : Wih_f;
  const float* Whh = dir ? Whh_b : Whh_f;
  const float* bih = dir ? bih_b : bih_f;
  const float* bhh = dir ? bhh_b : bhh_f;

  const int lane = tid & 63;
  const int wv   = tid >> 6;      // 0..7
  const int col  = lane & 15;
  const int quad = lane >> 4;
  const int jloc = wv * 16 + col; // this lane's hidden unit

  __shared__ __align__(16) _Float16 xA[CHUNK][XA_LD];
  __shared__ __align__(16) _Float16 xPL[CHUNK][XP_LD];
  __shared__ __align__(16) _Float16 hist[CHUNK + 1][HI_LD];

  const float LOG2E = 1.44269504f;

  // ---- stationary weight fragments, pre-scaled for exp2-native gates ----
  half8 whf[3][4];
  half8 wif[3][4];
#pragma unroll
  for (int g = 0; g < 3; ++g) {
    const float gs = (g == 2) ? 2.0f * LOG2E : LOG2E;
#pragma unroll
    for (int kt = 0; kt < 4; ++kt) {
      const float* sh = Whh + (size_t)(g * H_DIM + jloc) * H_DIM + kt * 32 + quad * 8;
      const float* si = Wih + (size_t)(g * H_DIM + jloc) * DX + kt * 32 + quad * 8;
      half8 vh, vi;
#pragma unroll
      for (int e = 0; e < 8; ++e) {
        vh[e] = (_Float16)(sh[e] * gs);
        vi[e] = (_Float16)(si[e] * gs);
      }
      whf[g][kt] = vh;
      wif[g][kt] = vi;
    }
  }
  const float bias_r = (bih[jloc] + bhh[jloc]) * LOG2E;
  const float bias_z = (bih[H_DIM + jloc] + bhh[H_DIM + jloc]) * LOG2E;
  const float bias_n = bih[2 * H_DIM + jloc] * (2.0f * LOG2E);
  const float bhn_s  = bhh[2 * H_DIM + jloc] * (2.0f * LOG2E);

  // ---- Wfc fragments for fused FC (waves 0..1) ----
  half8 fcf[4];
  if (wv < 2) {
#pragma unroll
    for (int kt = 0; kt < 4; ++kt) {
      half8 v;
#pragma unroll
      for (int e = 0; e < 8; ++e) {
        int k = kt * 32 + quad * 8 + e;
        v[e] = (col < K_CLS) ? (_Float16)Wfc[(size_t)col * (2 * H_DIM) + dir * H_DIM + k]
                             : (_Float16)0.f;
      }
      fcf[kt] = v;
    }
  }

  // A-operand fragments: only col==0 lanes ever load (A row 0 = h); rest are 0.
  half8 hz;
#pragma unroll
  for (int e = 0; e < 8; ++e) hz[e] = (_Float16)0.f;
  half8 haf0 = hz, haf1 = hz, haf2 = hz, haf3 = hz;

  if (tid < H_DIM) hist[0][tid] = (_Float16)0.f;

  // ---- x prefetch: thread covers row s_row, 8 consecutive floats ----
  const int s_row = tid >> 4;
  const int cb    = (tid & 15) * 8;
  float4 px0, px1;
  {
    int t0 = dir ? (T_LEN - 1 - s_row) : s_row;
    const float* xr = x + ((size_t)b * T_LEN + t0) * DX + cb;
    px0 = *(const float4*)xr;
    px1 = *(const float4*)(xr + 4);
  }

  float hold = 0.f;  // carried h for unit jloc (valid in quad==0 lanes)
  const floatx4 z4 = {0.f, 0.f, 0.f, 0.f};
  __syncthreads();

  for (int c = 0; c < NCHUNKS; ++c) {
    // ---- stage x chunk into LDS (f16) ----
    {
      half8 v;
      v[0] = (_Float16)px0.x; v[1] = (_Float16)px0.y; v[2] = (_Float16)px0.z; v[3] = (_Float16)px0.w;
      v[4] = (_Float16)px1.x; v[5] = (_Float16)px1.y; v[6] = (_Float16)px1.z; v[7] = (_Float16)px1.w;
      *(half8*)&xA[s_row][cb] = v;
    }
    LGKM_BARRIER();

    // ---- xp = (x @ Wih^T + bias), pre-scaled, packed [row][j*4+g] ----
#pragma unroll
    for (int mt = 0; mt < 2; ++mt) {
      half8 af[4];
#pragma unroll
      for (int kt = 0; kt < 4; ++kt)
        af[kt] = *(const half8*)&xA[mt * 16 + col][kt * 32 + quad * 8];
      floatx4 pr = z4, pz = z4, pn = z4;
#pragma unroll
      for (int kt = 0; kt < 4; ++kt) {
        pr = __builtin_amdgcn_mfma_f32_16x16x32_f16(af[kt], wif[0][kt], pr, 0, 0, 0);
        pz = __builtin_amdgcn_mfma_f32_16x16x32_f16(af[kt], wif[1][kt], pz, 0, 0, 0);
        pn = __builtin_amdgcn_mfma_f32_16x16x32_f16(af[kt], wif[2][kt], pn, 0, 0, 0);
      }
#pragma unroll
      for (int i = 0; i < 4; ++i) {
        half4 w;
        w[0] = (_Float16)(pr[i] + bias_r);
        w[1] = (_Float16)(pz[i] + bias_z);
        w[2] = (_Float16)(pn[i] + bias_n);
        w[3] = (_Float16)0.f;
        *(half4*)&xPL[mt * 16 + quad * 4 + i][jloc * 4] = w;
      }
    }

    // prefetch next chunk's x (stays in flight across the scan — no vmcnt drain)
    if (c + 1 < NCHUNKS) {
      int s  = (c + 1) * CHUNK + s_row;
      int t0 = dir ? (T_LEN - 1 - s) : s;
      const float* xr = x + ((size_t)b * T_LEN + t0) * DX + cb;
      px0 = *(const float4*)xr;
      px1 = *(const float4*)(xr + 4);
    }
    LGKM_BARRIER();

    uint2 xv = *(const uint2*)&xPL[0][jloc * 4];

    // ---- sequential scan ----
#pragma unroll 2
    for (int s = 0; s < CHUNK; ++s) {
      if (col == 0) {
        haf0 = *(const half8*)&hist[s][quad * 8];
        haf1 = *(const half8*)&hist[s][32 + quad * 8];
        haf2 = *(const half8*)&hist[s][64 + quad * 8];
        haf3 = *(const half8*)&hist[s][96 + quad * 8];
      }
      uint2 xvn = *(const uint2*)&xPL[(s + 1) & (CHUNK - 1)][jloc * 4];

      // 12 independent depth-1 MFMAs (r first so sigmoid(r) can start early)
      floatx4 cr0 = __builtin_amdgcn_mfma_f32_16x16x32_f16(haf0, whf[0][0], z4, 0, 0, 0);
      floatx4 cr1 = __builtin_amdgcn_mfma_f32_16x16x32_f16(haf1, whf[0][1], z4, 0, 0, 0);
      floatx4 cr2 = __builtin_amdgcn_mfma_f32_16x16x32_f16(haf2, whf[0][2], z4, 0, 0, 0);
      floatx4 cr3 = __builtin_amdgcn_mfma_f32_16x16x32_f16(haf3, whf[0][3], z4, 0, 0, 0);
      floatx4 cz0 = __builtin_amdgcn_mfma_f32_16x16x32_f16(haf0, whf[1][0], z4, 0, 0, 0);
      floatx4 cz1 = __builtin_amdgcn_mfma_f32_16x16x32_f16(haf1, whf[1][1], z4, 0, 0, 0);
      floatx4 cz2 = __builtin_amdgcn_mfma_f32_16x16x32_f16(haf2, whf[1][2], z4, 0, 0, 0);
      floatx4 cz3 = __builtin_amdgcn_mfma_f32_16x16x32_f16(haf3, whf[1][3], z4, 0, 0, 0);
      floatx4 cn0 = __builtin_amdgcn_mfma_f32_16x16x32_f16(haf0, whf[2][0], z4, 0, 0, 0);
      floatx4 cn1 = __builtin_amdgcn_mfma_f32_16x16x32_f16(haf1, whf[2][1], z4, 0, 0, 0);
      floatx4 cn2 = __builtin_amdgcn_mfma_f32_16x16x32_f16(haf2, whf[2][2], z4, 0, 0, 0);
      floatx4 cn3 = __builtin_amdgcn_mfma_f32_16x16x32_f16(haf3, whf[2][3], z4, 0, 0, 0);

      float ar = (cr0[0] + cr1[0]) + (cr2[0] + cr3[0]);  // valid in quad==0
      float az = (cz0[0] + cz1[0]) + (cz2[0] + cz3[0]);
      float an = (cn0[0] + cn1[0]) + (cn2[0] + cn3[0]);

      half2v x01 = __builtin_bit_cast(half2v, xv.x);  // xr, xz (log2e-scaled)
      half2v x23 = __builtin_bit_cast(half2v, xv.y);  // xn (2log2e-scaled)

      // sigmoid(x) = rcp(1 + 2^-y), y pre-scaled; saturates correctly w/o clamps
      float rr = __builtin_amdgcn_rcpf(1.f + __builtin_amdgcn_exp2f(-((float)x01.x + ar)));
      float zz = __builtin_amdgcn_rcpf(1.f + __builtin_amdgcn_exp2f(-((float)x01.y + az)));
      float yn = fmaf(rr, an + bhn_s, (float)x23.x);
      float t  = __builtin_amdgcn_exp2f(-fmaxf(yn, -80.f));   // guard t=inf -> NaN
      float nn = (1.f - t) * __builtin_amdgcn_rcpf(1.f + t);
      hold = nn + zz * (hold - nn);

      if (quad == 0) hist[s + 1][jloc] = (_Float16)hold;
      LGKM_BARRIER();
      xv = xvn;
    }

    // ---- fused FC for this chunk (waves 0..1) ----
    if (wv < 2) {
      floatx4 fa = z4;
#pragma unroll
      for (int kt = 0; kt < 4; ++kt) {
        half8 af = *(const half8*)&hist[1 + wv * 16 + col][kt * 32 + quad * 8];
        fa = __builtin_amdgcn_mfma_f32_16x16x32_f16(af, fcf[kt], fa, 0, 0, 0);
      }
      if (col < K_CLS) {
#pragma unroll
        for (int i = 0; i < 4; ++i) {
          int t  = c * CHUNK + wv * 16 + quad * 4 + i;
          int tt = dir ? (T_LEN - 1 - t) : t;
          atomicAdd(out + ((size_t)b * T_LEN + tt) * K_CLS + col, fa[i]);
        }
      }
    }
    // carry h into row 0 for the next chunk (ordered by next chunk's barriers)
    if (tid >= 256 && tid < 256 + H_DIM) hist[0][tid - 256] = hist[CHUNK][tid - 256];
  }
}

extern "C" void kernel_launch(void* const* d_in, const int* in_sizes, int n_in,
                              void* d_out, int out_size, void* d_ws, size_t ws_size,
                              hipStream_t stream) {
  (void)in_sizes; (void)n_in; (void)d_ws; (void)ws_size; (void)out_size;
  const float* x     = (const float*)d_in[0];
  const float* Wih_f = (const float*)d_in[1];
  const float* Whh_f = (const float*)d_in[2];
  const float* bih_f = (const float*)d_in[3];
  const float* bhh_f = (const float*)d_in[4];
  const float* Wih_b = (const float*)d_in[5];
  const float* Whh_b = (const float*)d_in[6];
  const float* bih_b = (const float*)d_in[7];
  const float* bhh_b = (const float*)d_in[8];
  const float* Wfc   = (const float*)d_in[9];
  const float* bfc   = (const float*)d_in[10];
  float* out = (float*)d_out;

  const int n_out = B_SZ * T_LEN * K_CLS;
  init_out_kernel<<<(n_out + 255) / 256, 256, 0, stream>>>(out, bfc);
  gru_bidir_kernel<<<B_SZ * 2, 512, 0, stream>>>(x, Wih_f, Whh_f, bih_f, bhh_f,
                                                 Wih_b, Whh_b, bih_b, bhh_b, Wfc, out);
}